// Round 7
// baseline (448.819 us; speedup 1.0000x reference)
//
#include <hip/hip_runtime.h>
#include <math.h>

// Problem constants (from reference)
#define BB 4
#define NN 1024
#define EE 1024
#define HH 16
#define DD 64
#define MAXLEN 512
#define EPS 1e-5f

typedef __attribute__((ext_vector_type(8))) __bf16 bf16x8;
typedef __attribute__((ext_vector_type(4))) float floatx4;
typedef __attribute__((ext_vector_type(8))) unsigned short ushort8;

__device__ __forceinline__ unsigned short f2bf(float f) {
    unsigned u = __float_as_uint(f);
    u += 0x7fffu + ((u >> 16) & 1u);   // RNE
    return (unsigned short)(u >> 16);
}
__device__ __forceinline__ float bf2f(unsigned short h) {
    return __uint_as_float(((unsigned)h) << 16);
}

// ---------------------------------------------------------------------------
// fp32 -> bf16 conversion (vectorized by 4)
// ---------------------------------------------------------------------------
__global__ __launch_bounds__(256) void f2bf_kernel(const float* __restrict__ in,
                                                   unsigned short* __restrict__ out,
                                                   int n4) {
    int i = blockIdx.x * 256 + threadIdx.x;
    if (i < n4) {
        float4 v = ((const float4*)in)[i];
        ushort4 o;
        o.x = f2bf(v.x); o.y = f2bf(v.y); o.z = f2bf(v.z); o.w = f2bf(v.w);
        ((ushort4*)out)[i] = o;
    }
}

// ---------------------------------------------------------------------------
// LayerNorm: one block (256 threads) per row of E=1024; bf16 output.
// ---------------------------------------------------------------------------
__global__ __launch_bounds__(256) void ln_kernel(const float* __restrict__ x,
                                                 const float* __restrict__ g,
                                                 const float* __restrict__ b,
                                                 unsigned short* __restrict__ out) {
    const int row = blockIdx.x;
    const float* xr = x + (size_t)row * EE;
    float s = 0.f, s2 = 0.f;
    for (int j = threadIdx.x; j < EE; j += 256) {
        float v = xr[j];
        s += v; s2 += v * v;
    }
    for (int off = 32; off > 0; off >>= 1) {
        s  += __shfl_xor(s, off);
        s2 += __shfl_xor(s2, off);
    }
    __shared__ float red[8];
    const int wave = threadIdx.x >> 6, lane = threadIdx.x & 63;
    if (lane == 0) { red[wave] = s; red[4 + wave] = s2; }
    __syncthreads();
    s  = red[0] + red[1] + red[2] + red[3];
    s2 = red[4] + red[5] + red[6] + red[7];
    const float mu  = s * (1.0f / EE);
    const float var = s2 * (1.0f / EE) - mu * mu;
    const float inv = rsqrtf(var + EPS);
    unsigned short* orow = out + (size_t)row * EE;
    for (int j = threadIdx.x; j < EE; j += 256) {
        orow[j] = f2bf((xr[j] - mu) * inv * g[j] + b[j]);
    }
}

// ---------------------------------------------------------------------------
// bf16 MFMA GEMM: C[M,Nc] = A[M,K] @ W[Nc,K]^T + bias (+res) (relu)
// Tile: 128 x TN (TN = 128 or 64), BK=64 (two 32-wide LDS sub-tiles for A).
// B (weights) is NOT staged in LDS: each wave streams its B fragments
// directly global->register with a one-iteration prefetch double-buffer
// (weights are L2/L3-resident). This halves LDS traffic (the measured
// limiter at TN=64) and lets B loads stay in flight across the barrier.
// Requires M%128==0, Nc%TN==0, K%128==0.
// ---------------------------------------------------------------------------
template <int TN, bool RELU, bool HAS_RES, bool OUT_BF16>
__global__ __launch_bounds__(256) void gemm_bf16_kernel(
    const unsigned short* __restrict__ A,
    const unsigned short* __restrict__ W,
    const float* __restrict__ bias,
    const float* res, void* Cout, int M, int Nc, int K) {
    constexpr int WN = TN / 2;       // wave N extent: 64 or 32
    constexpr int NJ = WN / 16;      // N frags per wave: 4 or 2
    __shared__ unsigned short As[2][128 * 32];

    const int tid  = threadIdx.x;
    const int lane = tid & 63;
    const int wv   = tid >> 6;
    const int row0 = blockIdx.y * 128;
    const int col0 = blockIdx.x * TN;
    const int waveM = (wv & 1) * 64;
    const int waveN = (wv >> 1) * WN;

    floatx4 acc[4][NJ];
#pragma unroll
    for (int i = 0; i < 4; ++i)
#pragma unroll
        for (int j = 0; j < NJ; ++j) acc[i][j] = (floatx4){0.f, 0.f, 0.f, 0.f};

    const int lrow = lane >> 2;        // staging: lane covers row lrow, 8 elems
    const int lk8  = (lane & 3) * 8;
    const int frow = lane & 15;        // fragment row
    const int kc8  = (lane >> 4) * 8;  // fragment k offset

    // Per-wave B base: row = col0 + waveN + t*16 + frow, elem offset kc8.
    const unsigned short* wbase = W + (size_t)(col0 + waveN + frow) * K + kc8;

    auto loadB = [&](int kk, bf16x8 (&dst)[2][NJ]) {
#pragma unroll
        for (int s = 0; s < 2; ++s)
#pragma unroll
            for (int t = 0; t < NJ; ++t)
                dst[s][t] = *(const bf16x8*)(wbase + (size_t)t * 16 * K + kk + s * 32);
    };
    auto stageA = [&](int kk0) {
#pragma unroll
        for (int s = 0; s < 2; ++s)
#pragma unroll
            for (int q = 0; q < 2; ++q) {
                const int r = wv * 32 + q * 16;
                const unsigned short* ga =
                    A + (size_t)(row0 + r + lrow) * K + kk0 + s * 32 + lk8;
                __builtin_amdgcn_global_load_lds(
                    (const __attribute__((address_space(1))) unsigned int*)ga,
                    (__attribute__((address_space(3))) unsigned int*)&As[s][r * 32],
                    16, 0, 0);
            }
    };
    auto compute = [&](bf16x8 (&bfr)[2][NJ]) {
#pragma unroll
        for (int s = 0; s < 2; ++s) {
            bf16x8 af[4];
#pragma unroll
            for (int t = 0; t < 4; ++t)
                af[t] = *(const bf16x8*)&As[s][(waveM + t * 16 + frow) * 32 + kc8];
#pragma unroll
            for (int i = 0; i < 4; ++i)
#pragma unroll
                for (int j = 0; j < NJ; ++j)
                    acc[i][j] = __builtin_amdgcn_mfma_f32_16x16x32_bf16(
                        af[i], bfr[s][j], acc[i][j], 0, 0, 0);
        }
    };

    bf16x8 b0[2][NJ], b1[2][NJ];
    loadB(0, b0);
    for (int k0 = 0; k0 < K; k0 += 128) {
        // half 1: compute with b0, prefetch b1
        stageA(k0);
        loadB(k0 + 64, b1);
        __syncthreads();
        compute(b0);
        __syncthreads();
        // half 2: compute with b1, prefetch b0 for next iteration
        stageA(k0 + 64);
        if (k0 + 128 < K) loadB(k0 + 128, b0);
        __syncthreads();
        compute(b1);
        __syncthreads();
    }

    float* Cf = (float*)Cout;
    unsigned short* Cb = (unsigned short*)Cout;
    const int crow = (lane >> 4) * 4;
    const int ccol = lane & 15;
#pragma unroll
    for (int j = 0; j < NJ; ++j) {
        const int n = col0 + waveN + j * 16 + ccol;
        const float bv = bias[n];
#pragma unroll
        for (int i = 0; i < 4; ++i) {
#pragma unroll
            for (int r = 0; r < 4; ++r) {
                const int m = row0 + waveM + i * 16 + crow + r;
                float v = acc[i][j][r] + bv;
                if (HAS_RES) v += res[(size_t)m * Nc + n];
                if (RELU) v = fmaxf(v, 0.f);
                if (OUT_BF16) Cb[(size_t)m * Nc + n] = f2bf(v);
                else          Cf[(size_t)m * Nc + n] = v;
            }
        }
    }
}

// ---------------------------------------------------------------------------
// Flash-style MFMA attention. rel_bias(i,j) finite only for 0 <= i-j < 512
// (causal sliding window). One block = 64 Q rows for (b,h); 4 waves, each
// owns 16 Q rows. QK^T and PV via mfma_f32_16x16x32_bf16; online softmax.
// ---------------------------------------------------------------------------
__global__ __launch_bounds__(256) void attn_mfma_kernel(
    const unsigned short* __restrict__ qkv,
    const float* __restrict__ rel_pos,
    unsigned short* __restrict__ o) {
    __shared__ unsigned short K_s[2][64][32];     // 8 KB
    __shared__ unsigned short V_s[64][72];        // 9 KB  [d][key]
    __shared__ unsigned short P_s[4][2][16][32];  // 8 KB  per-wave
    __shared__ float rel_s[MAXLEN];               // 2 KB

    const int qt = blockIdx.x, h = blockIdx.y, b = blockIdx.z;
    const int q0 = qt * 64;
    const int tid  = threadIdx.x;
    const int lane = tid & 63;
    const int w    = tid >> 6;
    const int quad = lane >> 4;
    const int c15  = lane & 15;

    rel_s[tid]       = rel_pos[h * MAXLEN + tid];
    rel_s[tid + 256] = rel_pos[h * MAXLEN + tid + 256];

    const size_t rowstride = 3 * EE;
    const size_t base_q = (size_t)(b * NN) * rowstride + h * DD;
    const size_t base_k = base_q + EE;
    const size_t base_v = base_q + 2 * EE;

    bf16x8 aq[2];
    {
        const unsigned short* qrow =
            qkv + base_q + (size_t)(q0 + w * 16 + c15) * rowstride + quad * 8;
        aq[0] = *(const bf16x8*)(qrow);
        aq[1] = *(const bf16x8*)(qrow + 32);
    }

    floatx4 Oacc[4];
#pragma unroll
    for (int j = 0; j < 4; ++j) Oacc[j] = (floatx4){0.f, 0.f, 0.f, 0.f};
    float m_r[4], l_r[4];
#pragma unroll
    for (int r = 0; r < 4; ++r) { m_r[r] = -1e30f; l_r[r] = 0.f; }

    const int jlo = max(0, q0 - (MAXLEN - 1));
    const int c0 = jlo >> 6;
    const int c1 = (q0 + 63) >> 6;

    for (int cc = c0; cc <= c1; ++cc) {
        const int jb0 = cc << 6;
        __syncthreads();

        {
            const int krow = w * 16 + (lane >> 2);
            const int dofs = (lane & 3) * 8;
            const unsigned short* gk =
                qkv + base_k + (size_t)(jb0 + krow) * rowstride + dofs;
            __builtin_amdgcn_global_load_lds(
                (const __attribute__((address_space(1))) unsigned int*)gk,
                (__attribute__((address_space(3))) unsigned int*)&K_s[0][w * 16][0],
                16, 0, 0);
            __builtin_amdgcn_global_load_lds(
                (const __attribute__((address_space(1))) unsigned int*)(gk + 32),
                (__attribute__((address_space(3))) unsigned int*)&K_s[1][w * 16][0],
                16, 0, 0);
        }
        {
            const int key = lane;
            const int d0  = w * 16;
            const unsigned short* gv =
                qkv + base_v + (size_t)(jb0 + key) * rowstride + d0;
            ushort8 va = *(const ushort8*)(gv);
            ushort8 vb = *(const ushort8*)(gv + 8);
#pragma unroll
            for (int ii = 0; ii < 8; ++ii) V_s[d0 + ii][key] = va[ii];
#pragma unroll
            for (int ii = 0; ii < 8; ++ii) V_s[d0 + 8 + ii][key] = vb[ii];
        }
        __syncthreads();

        floatx4 S[4];
#pragma unroll
        for (int jb = 0; jb < 4; ++jb) {
            S[jb] = (floatx4){0.f, 0.f, 0.f, 0.f};
            bf16x8 bk0 = *(const bf16x8*)&K_s[0][jb * 16 + c15][quad * 8];
            bf16x8 bk1 = *(const bf16x8*)&K_s[1][jb * 16 + c15][quad * 8];
            S[jb] = __builtin_amdgcn_mfma_f32_16x16x32_bf16(aq[0], bk0, S[jb], 0, 0, 0);
            S[jb] = __builtin_amdgcn_mfma_f32_16x16x32_bf16(aq[1], bk1, S[jb], 0, 0, 0);
        }

        const int i_base = q0 + w * 16 + quad * 4;
        float sv[4][4];
        float mc[4] = {-1e30f, -1e30f, -1e30f, -1e30f};
#pragma unroll
        for (int jb = 0; jb < 4; ++jb) {
            const int jg = jb0 + jb * 16 + c15;
#pragma unroll
            for (int r = 0; r < 4; ++r) {
                const int rel = (i_base + r) - jg;
                float s;
                if (rel >= 0 && rel < MAXLEN) s = S[jb][r] * 0.125f + rel_s[rel];
                else                          s = -1e30f;
                sv[jb][r] = s;
                mc[r] = fmaxf(mc[r], s);
            }
        }
#pragma unroll
        for (int off = 1; off < 16; off <<= 1)
#pragma unroll
            for (int r = 0; r < 4; ++r) mc[r] = fmaxf(mc[r], __shfl_xor(mc[r], off));

        float alpha[4], psum[4];
#pragma unroll
        for (int r = 0; r < 4; ++r) {
            const float mn = fmaxf(m_r[r], mc[r]);
            alpha[r] = __expf(m_r[r] - mn);
            m_r[r] = mn;
            psum[r] = 0.f;
        }
#pragma unroll
        for (int jb = 0; jb < 4; ++jb)
#pragma unroll
            for (int r = 0; r < 4; ++r) {
                const float p = __expf(sv[jb][r] - m_r[r]);
                sv[jb][r] = p;
                psum[r] += p;
            }
#pragma unroll
        for (int off = 1; off < 16; off <<= 1)
#pragma unroll
            for (int r = 0; r < 4; ++r) psum[r] += __shfl_xor(psum[r], off);
#pragma unroll
        for (int r = 0; r < 4; ++r) l_r[r] = l_r[r] * alpha[r] + psum[r];
#pragma unroll
        for (int jb = 0; jb < 4; ++jb)
#pragma unroll
            for (int r = 0; r < 4; ++r) Oacc[jb][r] *= alpha[r];

#pragma unroll
        for (int jb = 0; jb < 4; ++jb)
#pragma unroll
            for (int r = 0; r < 4; ++r)
                P_s[w][jb >> 1][quad * 4 + r][(jb & 1) * 16 + c15] = f2bf(sv[jb][r]);

        bf16x8 ap0 = *(const bf16x8*)&P_s[w][0][c15][quad * 8];
        bf16x8 ap1 = *(const bf16x8*)&P_s[w][1][c15][quad * 8];

#pragma unroll
        for (int jd = 0; jd < 4; ++jd) {
            bf16x8 bv0 = *(const bf16x8*)&V_s[jd * 16 + c15][quad * 8];
            bf16x8 bv1 = *(const bf16x8*)&V_s[jd * 16 + c15][32 + quad * 8];
            Oacc[jd] = __builtin_amdgcn_mfma_f32_16x16x32_bf16(ap0, bv0, Oacc[jd], 0, 0, 0);
            Oacc[jd] = __builtin_amdgcn_mfma_f32_16x16x32_bf16(ap1, bv1, Oacc[jd], 0, 0, 0);
        }
    }

    float inv[4];
#pragma unroll
    for (int r = 0; r < 4; ++r) inv[r] = 1.0f / l_r[r];
#pragma unroll
    for (int jd = 0; jd < 4; ++jd) {
#pragma unroll
        for (int r = 0; r < 4; ++r) {
            const int row = q0 + w * 16 + quad * 4 + r;
            const int col = h * DD + jd * 16 + c15;
            o[(size_t)(b * NN + row) * EE + col] = f2bf(Oacc[jd][r] * inv[r]);
        }
    }
}

// ---------------------------------------------------------------------------
// Launch
// ---------------------------------------------------------------------------
extern "C" void kernel_launch(void* const* d_in, const int* in_sizes, int n_in,
                              void* d_out, int out_size, void* d_ws, size_t ws_size,
                              hipStream_t stream) {
    const float* x         = (const float*)d_in[0];
    const float* rel_pos   = (const float*)d_in[1];
    const float* in_proj_w = (const float*)d_in[2];
    const float* in_proj_b = (const float*)d_in[3];
    const float* out_w     = (const float*)d_in[4];
    const float* out_b     = (const float*)d_in[5];
    const float* w1        = (const float*)d_in[6];
    const float* b1        = (const float*)d_in[7];
    const float* w2        = (const float*)d_in[8];
    const float* b2        = (const float*)d_in[9];
    const float* ln1_g     = (const float*)d_in[10];
    const float* ln1_b     = (const float*)d_in[11];
    const float* ln2_g     = (const float*)d_in[12];
    const float* ln2_b     = (const float*)d_in[13];
    float* out = (float*)d_out;

    char* wsb = (char*)d_ws;
    const size_t MB = 1024 * 1024;
    unsigned short* wqkv_b = (unsigned short*)(wsb + 0);        // 6 MB
    unsigned short* wout_b = (unsigned short*)(wsb + 6 * MB);   // 2 MB
    unsigned short* w1_b   = (unsigned short*)(wsb + 8 * MB);   // 8 MB
    unsigned short* w2_b   = (unsigned short*)(wsb + 16 * MB);  // 8 MB
    unsigned short* xn_b   = (unsigned short*)(wsb + 24 * MB);  // 8 MB (xn, then xm)
    unsigned short* qkv_b  = (unsigned short*)(wsb + 32 * MB);  // 24 MB
    unsigned short* h_b    = (unsigned short*)(wsb + 32 * MB);  // 32 MB (reuses qkv+o)
    unsigned short* o_b    = (unsigned short*)(wsb + 56 * MB);  // 8 MB

    const int Mrows = BB * NN;   // 4096

    f2bf_kernel<<<(3 * EE * EE / 4 + 255) / 256, 256, 0, stream>>>(in_proj_w, wqkv_b, 3 * EE * EE / 4);
    f2bf_kernel<<<(EE * EE / 4 + 255) / 256, 256, 0, stream>>>(out_w, wout_b, EE * EE / 4);
    f2bf_kernel<<<(4 * EE * EE / 4 + 255) / 256, 256, 0, stream>>>(w1, w1_b, 4 * EE * EE / 4);
    f2bf_kernel<<<(4 * EE * EE / 4 + 255) / 256, 256, 0, stream>>>(w2, w2_b, 4 * EE * EE / 4);

    ln_kernel<<<Mrows, 256, 0, stream>>>(x, ln1_g, ln1_b, xn_b);
    // QKV: N=3072, TN=128 -> 768 blocks (3/CU)
    gemm_bf16_kernel<128, false, false, true><<<dim3(3072 / 128, Mrows / 128), 256, 0, stream>>>(
        xn_b, wqkv_b, in_proj_b, nullptr, qkv_b, Mrows, 3 * EE, EE);
    attn_mfma_kernel<<<dim3(NN / 64, HH, BB), 256, 0, stream>>>(qkv_b, rel_pos, o_b);
    // out-proj + residual: N=1024, TN=64 -> 512 blocks (2/CU)
    gemm_bf16_kernel<64, false, true, false><<<dim3(EE / 64, Mrows / 128), 256, 0, stream>>>(
        o_b, wout_b, out_b, x, out, Mrows, EE, EE);
    ln_kernel<<<Mrows, 256, 0, stream>>>(out, ln2_g, ln2_b, xn_b);
    // FFN1: N=4096, TN=128 -> 1024 blocks (4/CU)
    gemm_bf16_kernel<128, true, false, true><<<dim3(4 * EE / 128, Mrows / 128), 256, 0, stream>>>(
        xn_b, w1_b, b1, nullptr, h_b, Mrows, 4 * EE, EE);
    // FFN2 + residual (in-place on d_out): N=1024, TN=64 -> 512 blocks (2/CU)
    gemm_bf16_kernel<64, false, true, false><<<dim3(EE / 64, Mrows / 128), 256, 0, stream>>>(
        h_b, w2_b, b2, out, out, Mrows, EE, 4 * EE);
}

// Round 8
// 364.020 us; speedup vs baseline: 1.2330x; 1.2330x over previous
//
#include <hip/hip_runtime.h>
#include <math.h>

// Problem constants (from reference)
#define BB 4
#define NN 1024
#define EE 1024
#define HH 16
#define DD 64
#define MAXLEN 512
#define EPS 1e-5f

typedef __attribute__((ext_vector_type(8))) __bf16 bf16x8;
typedef __attribute__((ext_vector_type(4))) float floatx4;
typedef __attribute__((ext_vector_type(8))) unsigned short ushort8;

__device__ __forceinline__ unsigned short f2bf(float f) {
    unsigned u = __float_as_uint(f);
    u += 0x7fffu + ((u >> 16) & 1u);   // RNE
    return (unsigned short)(u >> 16);
}
__device__ __forceinline__ float bf2f(unsigned short h) {
    return __uint_as_float(((unsigned)h) << 16);
}

// ---------------------------------------------------------------------------
// fp32 -> bf16 conversion (vectorized by 4)
// ---------------------------------------------------------------------------
__global__ __launch_bounds__(256) void f2bf_kernel(const float* __restrict__ in,
                                                   unsigned short* __restrict__ out,
                                                   int n4) {
    int i = blockIdx.x * 256 + threadIdx.x;
    if (i < n4) {
        float4 v = ((const float4*)in)[i];
        ushort4 o;
        o.x = f2bf(v.x); o.y = f2bf(v.y); o.z = f2bf(v.z); o.w = f2bf(v.w);
        ((ushort4*)out)[i] = o;
    }
}

// ---------------------------------------------------------------------------
// LayerNorm: one block (256 threads) per row of E=1024; bf16 output.
// ---------------------------------------------------------------------------
__global__ __launch_bounds__(256) void ln_kernel(const float* __restrict__ x,
                                                 const float* __restrict__ g,
                                                 const float* __restrict__ b,
                                                 unsigned short* __restrict__ out) {
    const int row = blockIdx.x;
    const float* xr = x + (size_t)row * EE;
    float s = 0.f, s2 = 0.f;
    for (int j = threadIdx.x; j < EE; j += 256) {
        float v = xr[j];
        s += v; s2 += v * v;
    }
    for (int off = 32; off > 0; off >>= 1) {
        s  += __shfl_xor(s, off);
        s2 += __shfl_xor(s2, off);
    }
    __shared__ float red[8];
    const int wave = threadIdx.x >> 6, lane = threadIdx.x & 63;
    if (lane == 0) { red[wave] = s; red[4 + wave] = s2; }
    __syncthreads();
    s  = red[0] + red[1] + red[2] + red[3];
    s2 = red[4] + red[5] + red[6] + red[7];
    const float mu  = s * (1.0f / EE);
    const float var = s2 * (1.0f / EE) - mu * mu;
    const float inv = rsqrtf(var + EPS);
    unsigned short* orow = out + (size_t)row * EE;
    for (int j = threadIdx.x; j < EE; j += 256) {
        orow[j] = f2bf((xr[j] - mu) * inv * g[j] + b[j]);
    }
}

// ---------------------------------------------------------------------------
// bf16 MFMA GEMM: C[M,Nc] = A[M,K] @ W[Nc,K]^T + bias (+res) (relu)
// Tile: 128 x TN (TN = 128 or 64). BK = 32*NSUB per iteration, staged as
// NSUB 32-wide sub-tiles in separate LDS regions (conflict-free 64-B pitch).
// NSUB=4 (BK=128) for grid-capped shapes (TN=64, 512 blocks = 2 blocks/CU:
// extra LDS costs no occupancy, halves barrier-drain events).
// Requires M%128==0, Nc%TN==0, K%(32*NSUB)==0.
// ---------------------------------------------------------------------------
template <int TN, int NSUB, bool RELU, bool HAS_RES, bool OUT_BF16>
__global__ __launch_bounds__(256) void gemm_bf16_kernel(
    const unsigned short* __restrict__ A,
    const unsigned short* __restrict__ W,
    const float* __restrict__ bias,
    const float* res, void* Cout, int M, int Nc, int K) {
    constexpr int WN = TN / 2;       // wave N extent: 64 or 32
    constexpr int NJ = WN / 16;      // N frags per wave: 4 or 2
    constexpr int BI = TN / 64;      // B staging issues per wave per subtile
    __shared__ unsigned short As[NSUB][128 * 32];
    __shared__ unsigned short Bs[NSUB][TN * 32];

    const int tid  = threadIdx.x;
    const int lane = tid & 63;
    const int wv   = tid >> 6;
    const int row0 = blockIdx.y * 128;
    const int col0 = blockIdx.x * TN;
    const int waveM = (wv & 1) * 64;
    const int waveN = (wv >> 1) * WN;

    floatx4 acc[4][NJ];
#pragma unroll
    for (int i = 0; i < 4; ++i)
#pragma unroll
        for (int j = 0; j < NJ; ++j) acc[i][j] = (floatx4){0.f, 0.f, 0.f, 0.f};

    const int lrow = lane >> 2;        // staging: lane covers row lrow, 8 elems
    const int lk8  = (lane & 3) * 8;
    const int frow = lane & 15;        // fragment row
    const int kc8  = (lane >> 4) * 8;  // fragment k offset

    for (int k0 = 0; k0 < K; k0 += 32 * NSUB) {
#pragma unroll
        for (int s = 0; s < NSUB; ++s) {
            const int kk = k0 + s * 32;
#pragma unroll
            for (int q = 0; q < 2; ++q) {
                const int r = wv * 32 + q * 16;
                const unsigned short* ga = A + (size_t)(row0 + r + lrow) * K + kk + lk8;
                __builtin_amdgcn_global_load_lds(
                    (const __attribute__((address_space(1))) unsigned int*)ga,
                    (__attribute__((address_space(3))) unsigned int*)&As[s][r * 32], 16, 0, 0);
            }
#pragma unroll
            for (int q = 0; q < BI; ++q) {
                const int r = wv * (16 * BI) + q * 16;
                const unsigned short* gb = W + (size_t)(col0 + r + lrow) * K + kk + lk8;
                __builtin_amdgcn_global_load_lds(
                    (const __attribute__((address_space(1))) unsigned int*)gb,
                    (__attribute__((address_space(3))) unsigned int*)&Bs[s][r * 32], 16, 0, 0);
            }
        }
        __syncthreads();   // all sub-tiles resident

#pragma unroll
        for (int s = 0; s < NSUB; ++s) {
            bf16x8 af[4], bfr[NJ];
#pragma unroll
            for (int t = 0; t < 4; ++t)
                af[t] = *(const bf16x8*)&As[s][(waveM + t * 16 + frow) * 32 + kc8];
#pragma unroll
            for (int t = 0; t < NJ; ++t)
                bfr[t] = *(const bf16x8*)&Bs[s][(waveN + t * 16 + frow) * 32 + kc8];
#pragma unroll
            for (int i = 0; i < 4; ++i)
#pragma unroll
                for (int j = 0; j < NJ; ++j)
                    acc[i][j] = __builtin_amdgcn_mfma_f32_16x16x32_bf16(
                        af[i], bfr[j], acc[i][j], 0, 0, 0);
        }
        __syncthreads();   // tiles free for overwrite
    }

    float* Cf = (float*)Cout;
    unsigned short* Cb = (unsigned short*)Cout;
    const int crow = (lane >> 4) * 4;
    const int ccol = lane & 15;
#pragma unroll
    for (int j = 0; j < NJ; ++j) {
        const int n = col0 + waveN + j * 16 + ccol;
        const float bv = bias[n];
#pragma unroll
        for (int i = 0; i < 4; ++i) {
#pragma unroll
            for (int r = 0; r < 4; ++r) {
                const int m = row0 + waveM + i * 16 + crow + r;
                float v = acc[i][j][r] + bv;
                if (HAS_RES) v += res[(size_t)m * Nc + n];
                if (RELU) v = fmaxf(v, 0.f);
                if (OUT_BF16) Cb[(size_t)m * Nc + n] = f2bf(v);
                else          Cf[(size_t)m * Nc + n] = v;
            }
        }
    }
}

// ---------------------------------------------------------------------------
// Flash-style MFMA attention. rel_bias(i,j) finite only for 0 <= i-j < 512
// (causal sliding window). One block = 64 Q rows for (b,h); 4 waves, each
// owns 16 Q rows. QK^T and PV via mfma_f32_16x16x32_bf16; online softmax.
// ---------------------------------------------------------------------------
__global__ __launch_bounds__(256) void attn_mfma_kernel(
    const unsigned short* __restrict__ qkv,
    const float* __restrict__ rel_pos,
    unsigned short* __restrict__ o) {
    __shared__ unsigned short K_s[2][64][32];     // 8 KB
    __shared__ unsigned short V_s[64][72];        // 9 KB  [d][key]
    __shared__ unsigned short P_s[4][2][16][32];  // 8 KB  per-wave
    __shared__ float rel_s[MAXLEN];               // 2 KB

    const int qt = blockIdx.x, h = blockIdx.y, b = blockIdx.z;
    const int q0 = qt * 64;
    const int tid  = threadIdx.x;
    const int lane = tid & 63;
    const int w    = tid >> 6;
    const int quad = lane >> 4;
    const int c15  = lane & 15;

    rel_s[tid]       = rel_pos[h * MAXLEN + tid];
    rel_s[tid + 256] = rel_pos[h * MAXLEN + tid + 256];

    const size_t rowstride = 3 * EE;
    const size_t base_q = (size_t)(b * NN) * rowstride + h * DD;
    const size_t base_k = base_q + EE;
    const size_t base_v = base_q + 2 * EE;

    bf16x8 aq[2];
    {
        const unsigned short* qrow =
            qkv + base_q + (size_t)(q0 + w * 16 + c15) * rowstride + quad * 8;
        aq[0] = *(const bf16x8*)(qrow);
        aq[1] = *(const bf16x8*)(qrow + 32);
    }

    floatx4 Oacc[4];
#pragma unroll
    for (int j = 0; j < 4; ++j) Oacc[j] = (floatx4){0.f, 0.f, 0.f, 0.f};
    float m_r[4], l_r[4];
#pragma unroll
    for (int r = 0; r < 4; ++r) { m_r[r] = -1e30f; l_r[r] = 0.f; }

    const int jlo = max(0, q0 - (MAXLEN - 1));
    const int c0 = jlo >> 6;
    const int c1 = (q0 + 63) >> 6;

    for (int cc = c0; cc <= c1; ++cc) {
        const int jb0 = cc << 6;
        __syncthreads();

        {
            const int krow = w * 16 + (lane >> 2);
            const int dofs = (lane & 3) * 8;
            const unsigned short* gk =
                qkv + base_k + (size_t)(jb0 + krow) * rowstride + dofs;
            __builtin_amdgcn_global_load_lds(
                (const __attribute__((address_space(1))) unsigned int*)gk,
                (__attribute__((address_space(3))) unsigned int*)&K_s[0][w * 16][0],
                16, 0, 0);
            __builtin_amdgcn_global_load_lds(
                (const __attribute__((address_space(1))) unsigned int*)(gk + 32),
                (__attribute__((address_space(3))) unsigned int*)&K_s[1][w * 16][0],
                16, 0, 0);
        }
        {
            const int key = lane;
            const int d0  = w * 16;
            const unsigned short* gv =
                qkv + base_v + (size_t)(jb0 + key) * rowstride + d0;
            ushort8 va = *(const ushort8*)(gv);
            ushort8 vb = *(const ushort8*)(gv + 8);
#pragma unroll
            for (int ii = 0; ii < 8; ++ii) V_s[d0 + ii][key] = va[ii];
#pragma unroll
            for (int ii = 0; ii < 8; ++ii) V_s[d0 + 8 + ii][key] = vb[ii];
        }
        __syncthreads();

        floatx4 S[4];
#pragma unroll
        for (int jb = 0; jb < 4; ++jb) {
            S[jb] = (floatx4){0.f, 0.f, 0.f, 0.f};
            bf16x8 bk0 = *(const bf16x8*)&K_s[0][jb * 16 + c15][quad * 8];
            bf16x8 bk1 = *(const bf16x8*)&K_s[1][jb * 16 + c15][quad * 8];
            S[jb] = __builtin_amdgcn_mfma_f32_16x16x32_bf16(aq[0], bk0, S[jb], 0, 0, 0);
            S[jb] = __builtin_amdgcn_mfma_f32_16x16x32_bf16(aq[1], bk1, S[jb], 0, 0, 0);
        }

        const int i_base = q0 + w * 16 + quad * 4;
        float sv[4][4];
        float mc[4] = {-1e30f, -1e30f, -1e30f, -1e30f};
#pragma unroll
        for (int jb = 0; jb < 4; ++jb) {
            const int jg = jb0 + jb * 16 + c15;
#pragma unroll
            for (int r = 0; r < 4; ++r) {
                const int rel = (i_base + r) - jg;
                float s;
                if (rel >= 0 && rel < MAXLEN) s = S[jb][r] * 0.125f + rel_s[rel];
                else                          s = -1e30f;
                sv[jb][r] = s;
                mc[r] = fmaxf(mc[r], s);
            }
        }
#pragma unroll
        for (int off = 1; off < 16; off <<= 1)
#pragma unroll
            for (int r = 0; r < 4; ++r) mc[r] = fmaxf(mc[r], __shfl_xor(mc[r], off));

        float alpha[4], psum[4];
#pragma unroll
        for (int r = 0; r < 4; ++r) {
            const float mn = fmaxf(m_r[r], mc[r]);
            alpha[r] = __expf(m_r[r] - mn);
            m_r[r] = mn;
            psum[r] = 0.f;
        }
#pragma unroll
        for (int jb = 0; jb < 4; ++jb)
#pragma unroll
            for (int r = 0; r < 4; ++r) {
                const float p = __expf(sv[jb][r] - m_r[r]);
                sv[jb][r] = p;
                psum[r] += p;
            }
#pragma unroll
        for (int off = 1; off < 16; off <<= 1)
#pragma unroll
            for (int r = 0; r < 4; ++r) psum[r] += __shfl_xor(psum[r], off);
#pragma unroll
        for (int r = 0; r < 4; ++r) l_r[r] = l_r[r] * alpha[r] + psum[r];
#pragma unroll
        for (int jb = 0; jb < 4; ++jb)
#pragma unroll
            for (int r = 0; r < 4; ++r) Oacc[jb][r] *= alpha[r];

#pragma unroll
        for (int jb = 0; jb < 4; ++jb)
#pragma unroll
            for (int r = 0; r < 4; ++r)
                P_s[w][jb >> 1][quad * 4 + r][(jb & 1) * 16 + c15] = f2bf(sv[jb][r]);

        bf16x8 ap0 = *(const bf16x8*)&P_s[w][0][c15][quad * 8];
        bf16x8 ap1 = *(const bf16x8*)&P_s[w][1][c15][quad * 8];

#pragma unroll
        for (int jd = 0; jd < 4; ++jd) {
            bf16x8 bv0 = *(const bf16x8*)&V_s[jd * 16 + c15][quad * 8];
            bf16x8 bv1 = *(const bf16x8*)&V_s[jd * 16 + c15][32 + quad * 8];
            Oacc[jd] = __builtin_amdgcn_mfma_f32_16x16x32_bf16(ap0, bv0, Oacc[jd], 0, 0, 0);
            Oacc[jd] = __builtin_amdgcn_mfma_f32_16x16x32_bf16(ap1, bv1, Oacc[jd], 0, 0, 0);
        }
    }

    float inv[4];
#pragma unroll
    for (int r = 0; r < 4; ++r) inv[r] = 1.0f / l_r[r];
#pragma unroll
    for (int jd = 0; jd < 4; ++jd) {
#pragma unroll
        for (int r = 0; r < 4; ++r) {
            const int row = q0 + w * 16 + quad * 4 + r;
            const int col = h * DD + jd * 16 + c15;
            o[(size_t)(b * NN + row) * EE + col] = f2bf(Oacc[jd][r] * inv[r]);
        }
    }
}

// ---------------------------------------------------------------------------
// Launch
// ---------------------------------------------------------------------------
extern "C" void kernel_launch(void* const* d_in, const int* in_sizes, int n_in,
                              void* d_out, int out_size, void* d_ws, size_t ws_size,
                              hipStream_t stream) {
    const float* x         = (const float*)d_in[0];
    const float* rel_pos   = (const float*)d_in[1];
    const float* in_proj_w = (const float*)d_in[2];
    const float* in_proj_b = (const float*)d_in[3];
    const float* out_w     = (const float*)d_in[4];
    const float* out_b     = (const float*)d_in[5];
    const float* w1        = (const float*)d_in[6];
    const float* b1        = (const float*)d_in[7];
    const float* w2        = (const float*)d_in[8];
    const float* b2        = (const float*)d_in[9];
    const float* ln1_g     = (const float*)d_in[10];
    const float* ln1_b     = (const float*)d_in[11];
    const float* ln2_g     = (const float*)d_in[12];
    const float* ln2_b     = (const float*)d_in[13];
    float* out = (float*)d_out;

    char* wsb = (char*)d_ws;
    const size_t MB = 1024 * 1024;
    unsigned short* wqkv_b = (unsigned short*)(wsb + 0);        // 6 MB
    unsigned short* wout_b = (unsigned short*)(wsb + 6 * MB);   // 2 MB
    unsigned short* w1_b   = (unsigned short*)(wsb + 8 * MB);   // 8 MB
    unsigned short* w2_b   = (unsigned short*)(wsb + 16 * MB);  // 8 MB
    unsigned short* xn_b   = (unsigned short*)(wsb + 24 * MB);  // 8 MB (xn, then xm)
    unsigned short* qkv_b  = (unsigned short*)(wsb + 32 * MB);  // 24 MB
    unsigned short* h_b    = (unsigned short*)(wsb + 32 * MB);  // 32 MB (reuses qkv+o)
    unsigned short* o_b    = (unsigned short*)(wsb + 56 * MB);  // 8 MB

    const int Mrows = BB * NN;   // 4096

    f2bf_kernel<<<(3 * EE * EE / 4 + 255) / 256, 256, 0, stream>>>(in_proj_w, wqkv_b, 3 * EE * EE / 4);
    f2bf_kernel<<<(EE * EE / 4 + 255) / 256, 256, 0, stream>>>(out_w, wout_b, EE * EE / 4);
    f2bf_kernel<<<(4 * EE * EE / 4 + 255) / 256, 256, 0, stream>>>(w1, w1_b, 4 * EE * EE / 4);
    f2bf_kernel<<<(4 * EE * EE / 4 + 255) / 256, 256, 0, stream>>>(w2, w2_b, 4 * EE * EE / 4);

    ln_kernel<<<Mrows, 256, 0, stream>>>(x, ln1_g, ln1_b, xn_b);
    // QKV: N=3072, TN=128, BK=64 -> 768 blocks (3/CU)
    gemm_bf16_kernel<128, 2, false, false, true><<<dim3(3072 / 128, Mrows / 128), 256, 0, stream>>>(
        xn_b, wqkv_b, in_proj_b, nullptr, qkv_b, Mrows, 3 * EE, EE);
    attn_mfma_kernel<<<dim3(NN / 64, HH, BB), 256, 0, stream>>>(qkv_b, rel_pos, o_b);
    // out-proj + residual: N=1024, TN=64, BK=128 (grid-capped at 2/CU; 48 KB LDS free)
    gemm_bf16_kernel<64, 4, false, true, false><<<dim3(EE / 64, Mrows / 128), 256, 0, stream>>>(
        o_b, wout_b, out_b, x, out, Mrows, EE, EE);
    ln_kernel<<<Mrows, 256, 0, stream>>>(out, ln2_g, ln2_b, xn_b);
    // FFN1: N=4096, TN=128, BK=64 -> 1024 blocks (4/CU)
    gemm_bf16_kernel<128, 2, true, false, true><<<dim3(4 * EE / 128, Mrows / 128), 256, 0, stream>>>(
        xn_b, w1_b, b1, nullptr, h_b, Mrows, 4 * EE, EE);
    // FFN2 + residual (in-place on d_out): N=1024, TN=64, BK=128
    gemm_bf16_kernel<64, 4, false, true, false><<<dim3(EE / 64, Mrows / 128), 256, 0, stream>>>(
        h_b, w2_b, b2, out, out, Mrows, EE, 4 * EE);
}